// Round 1
// baseline (700.413 us; speedup 1.0000x reference)
//
#include <hip/hip_runtime.h>
#include <hip/hip_bf16.h>

typedef __bf16 bf16;
typedef bf16  bf16x8 __attribute__((ext_vector_type(8)));
typedef float f32x4  __attribute__((ext_vector_type(4)));

#define DEVINL static __device__ __forceinline__

constexpr int C_ = 192, H_ = 256, W_ = 256;
constexpr int NH_ = 6;
constexpr int NWIN = 4096;          // 4 * 32 * 32 windows
constexpr int THREADS = 768;        // 12 waves: 2 per head

// LDS layout (bf16 element strides chosen so every ds_read_b128 is 16B-aligned)
constexpr int XS_STRIDE = 200;      // x window [64 tok][192 ch] + pad
constexpr int QK_STRIDE = 40;       // q/k [64 tok][32 hd] + pad
constexpr int VT_STRIDE = 72;       // vT [32 hd][64 tok] + pad
constexpr int P_STRIDE  = 72;       // p  [64 q ][64 key] + pad (overlays q+k)
constexpr int OUT_STRIDE = 67;      // out_lds f32 [192 ch][64 tok] + pad (overlays heads)

constexpr int XS_BYTES   = 64 * XS_STRIDE * 2;                                   // 25600
constexpr int HEAD_BYTES = (64*QK_STRIDE + 64*QK_STRIDE + 32*VT_STRIDE) * 2;     // 14848
constexpr int HEADS_BASE = XS_BYTES;
constexpr int LDS_BYTES  = HEADS_BASE + NH_ * HEAD_BYTES;                        // 114688

DEVINL bf16x8 cvt8(const float* p) {
    float4 f0 = *(const float4*)p;
    float4 f1 = *(const float4*)(p + 4);
    bf16x8 r;
    r[0] = (bf16)f0.x; r[1] = (bf16)f0.y; r[2] = (bf16)f0.z; r[3] = (bf16)f0.w;
    r[4] = (bf16)f1.x; r[5] = (bf16)f1.y; r[6] = (bf16)f1.z; r[7] = (bf16)f1.w;
    return r;
}

// One block per 8x8 window. 12 waves: wave = 2*head + half.
// MFMA 16x16x32 bf16 layouts (HW-verified per guide):
//   A[row=lane&15][k=(lane>>4)*8+j]  B[k=(lane>>4)*8+j][col=lane&15]
//   D[row=(lane>>4)*4+r][col=lane&15]
__global__ __launch_bounds__(THREADS, 1)
void block_attn(const float* __restrict__ x,
                const float* __restrict__ wqkv,   // [576][192]
                const float* __restrict__ bqkv,   // [576]
                const float* __restrict__ wout,   // [192][192]
                const float* __restrict__ bout,   // [192]
                float* __restrict__ out)
{
    extern __shared__ char smem[];
    bf16* xs = (bf16*)smem;                       // [64][XS_STRIDE]; later attn-out overlay

    const int tid  = threadIdx.x;
    const int lane = tid & 63;
    const int wv   = tid >> 6;       // 0..11
    const int h    = wv >> 1;        // head 0..5
    const int half = wv & 1;         // row-half of the window
    const int g    = lane >> 4;      // 0..3
    const int c    = lane & 15;

    const int win = blockIdx.x;
    const int b  = win >> 10;
    const int wh = (win >> 5) & 31;
    const int ww = win & 31;

    const size_t pixbase = ((size_t)b * C_) * (H_ * W_) + (size_t)(wh * 8) * W_ + ww * 8;
    const float* xwin = x   + pixbase;
    float*       owin = out + pixbase;

    // ---------------- phase 0: gather x window -> LDS bf16 [tok][ch]
    for (int i = tid; i < 64 * C_; i += THREADS) {
        int ch = i >> 6, tok = i & 63;
        xs[tok * XS_STRIDE + ch] = (bf16)xwin[(size_t)ch * (H_ * W_) + (tok >> 3) * W_ + (tok & 7)];
    }
    __syncthreads();

    bf16* qh  = (bf16*)(smem + HEADS_BASE + h * HEAD_BYTES);  // [64][QK_STRIDE]
    bf16* kh  = qh + 64 * QK_STRIDE;                          // [64][QK_STRIDE]
    bf16* vth = kh + 64 * QK_STRIDE;                          // [32][VT_STRIDE]
    bf16* ph  = qh;                                           // p overlays q+k (after barrier)

    const int colt[6] = {32*h, 32*h+16, 192+32*h, 192+32*h+16, 384+32*h, 384+32*h+16};
    const int m0 = 2 * half;  // this wave's row tiles: m0, m0+1

    // ---------------- phase 1: QKV projection for this head (96 cols), K=192
    f32x4 acc[2][6];
    #pragma unroll
    for (int i2 = 0; i2 < 2; ++i2)
        #pragma unroll
        for (int ct = 0; ct < 6; ++ct) acc[i2][ct] = (f32x4){0.f, 0.f, 0.f, 0.f};

    #pragma unroll
    for (int ks = 0; ks < 6; ++ks) {
        const int k0 = ks * 32 + g * 8;
        bf16x8 a0 = *(const bf16x8*)&xs[(16*m0      + c) * XS_STRIDE + k0];
        bf16x8 a1 = *(const bf16x8*)&xs[(16*m0 + 16 + c) * XS_STRIDE + k0];
        #pragma unroll
        for (int ct = 0; ct < 6; ++ct) {
            bf16x8 bw = cvt8(wqkv + (size_t)(colt[ct] + c) * C_ + k0);  // W[col][k..k+7]
            acc[0][ct] = __builtin_amdgcn_mfma_f32_16x16x32_bf16(a0, bw, acc[0][ct], 0, 0, 0);
            acc[1][ct] = __builtin_amdgcn_mfma_f32_16x16x32_bf16(a1, bw, acc[1][ct], 0, 0, 0);
        }
    }

    // bias + store q (pre-scaled), k, vT to LDS
    #pragma unroll
    for (int i2 = 0; i2 < 2; ++i2) {
        const int trow = 16 * (m0 + i2) + 4 * g;
        #pragma unroll
        for (int ct = 0; ct < 6; ++ct) {
            const float bias = bqkv[colt[ct] + c];
            #pragma unroll
            for (int r = 0; r < 4; ++r) {
                float v = acc[i2][ct][r] + bias;
                int tok = trow + r;
                if (ct < 2)       qh[tok * QK_STRIDE + 16*ct + c] = (bf16)(v * 0.17677669529663687f);
                else if (ct < 4)  kh[tok * QK_STRIDE + 16*(ct-2) + c] = (bf16)v;
                else              vth[(16*(ct-4) + c) * VT_STRIDE + tok] = (bf16)v;  // transposed
            }
        }
    }
    __syncthreads();

    // ---------------- phase 2: scores = q @ k^T (K=32, one MFMA per tile) + softmax
    f32x4 sc[2][4];
    {
        const f32x4 zf = (f32x4){0.f, 0.f, 0.f, 0.f};
        bf16x8 qa0 = *(const bf16x8*)&qh[(16*m0      + c) * QK_STRIDE + g * 8];
        bf16x8 qa1 = *(const bf16x8*)&qh[(16*m0 + 16 + c) * QK_STRIDE + g * 8];
        #pragma unroll
        for (int ct = 0; ct < 4; ++ct) {
            bf16x8 kb = *(const bf16x8*)&kh[(16*ct + c) * QK_STRIDE + g * 8];
            sc[0][ct] = __builtin_amdgcn_mfma_f32_16x16x32_bf16(qa0, kb, zf, 0, 0, 0);
            sc[1][ct] = __builtin_amdgcn_mfma_f32_16x16x32_bf16(qa1, kb, zf, 0, 0, 0);
        }
    }
    // softmax rows live across 16 lanes (same g group), 4 regs (key tiles)
    #pragma unroll
    for (int i2 = 0; i2 < 2; ++i2) {
        #pragma unroll
        for (int r = 0; r < 4; ++r) {
            float mx = fmaxf(fmaxf(sc[i2][0][r], sc[i2][1][r]), fmaxf(sc[i2][2][r], sc[i2][3][r]));
            mx = fmaxf(mx, __shfl_xor(mx, 1, 16));
            mx = fmaxf(mx, __shfl_xor(mx, 2, 16));
            mx = fmaxf(mx, __shfl_xor(mx, 4, 16));
            mx = fmaxf(mx, __shfl_xor(mx, 8, 16));
            float e0 = __expf(sc[i2][0][r] - mx);
            float e1 = __expf(sc[i2][1][r] - mx);
            float e2 = __expf(sc[i2][2][r] - mx);
            float e3 = __expf(sc[i2][3][r] - mx);
            float s = e0 + e1 + e2 + e3;
            s += __shfl_xor(s, 1, 16);
            s += __shfl_xor(s, 2, 16);
            s += __shfl_xor(s, 4, 16);
            s += __shfl_xor(s, 8, 16);
            float inv = 1.0f / s;
            sc[i2][0][r] = e0 * inv; sc[i2][1][r] = e1 * inv;
            sc[i2][2][r] = e2 * inv; sc[i2][3][r] = e3 * inv;
        }
    }
    __syncthreads();  // all waves done READING q/k before p overlays them

    #pragma unroll
    for (int i2 = 0; i2 < 2; ++i2)
        #pragma unroll
        for (int ct = 0; ct < 4; ++ct)
            #pragma unroll
            for (int r = 0; r < 4; ++r)
                ph[(16*(m0+i2) + 4*g + r) * P_STRIDE + 16*ct + c] = (bf16)sc[i2][ct][r];

    // ---------------- phase 3: out_h = p @ v  (K=64 keys; reads only rows this wave wrote)
    f32x4 oacc[2][2];
    #pragma unroll
    for (int i2 = 0; i2 < 2; ++i2)
        #pragma unroll
        for (int ct2 = 0; ct2 < 2; ++ct2) oacc[i2][ct2] = (f32x4){0.f, 0.f, 0.f, 0.f};

    #pragma unroll
    for (int ks2 = 0; ks2 < 2; ++ks2) {
        bf16x8 pa0 = *(const bf16x8*)&ph[(16*m0      + c) * P_STRIDE + ks2*32 + g*8];
        bf16x8 pa1 = *(const bf16x8*)&ph[(16*m0 + 16 + c) * P_STRIDE + ks2*32 + g*8];
        #pragma unroll
        for (int ct2 = 0; ct2 < 2; ++ct2) {
            bf16x8 vb = *(const bf16x8*)&vth[(16*ct2 + c) * VT_STRIDE + ks2*32 + g*8];
            oacc[0][ct2] = __builtin_amdgcn_mfma_f32_16x16x32_bf16(pa0, vb, oacc[0][ct2], 0, 0, 0);
            oacc[1][ct2] = __builtin_amdgcn_mfma_f32_16x16x32_bf16(pa1, vb, oacc[1][ct2], 0, 0, 0);
        }
    }
    bf16* attn = xs;  // attn-out [64 tok][192 ch] overlays xs (dead since phase 1)
    #pragma unroll
    for (int i2 = 0; i2 < 2; ++i2)
        #pragma unroll
        for (int ct2 = 0; ct2 < 2; ++ct2)
            #pragma unroll
            for (int r = 0; r < 4; ++r)
                attn[(16*(m0+i2) + 4*g + r) * XS_STRIDE + 32*h + 16*ct2 + c] = (bf16)oacc[i2][ct2][r];
    __syncthreads();

    // ---------------- phase 4: out-proj, wave wv owns cols [16*wv, 16*wv+16)
    f32x4 oo[4];
    #pragma unroll
    for (int m = 0; m < 4; ++m) oo[m] = (f32x4){0.f, 0.f, 0.f, 0.f};
    const int colb = 16 * wv;
    #pragma unroll
    for (int ks = 0; ks < 6; ++ks) {
        const int k0 = ks * 32 + g * 8;
        bf16x8 bw = cvt8(wout + (size_t)(colb + c) * C_ + k0);
        #pragma unroll
        for (int m = 0; m < 4; ++m) {
            bf16x8 a = *(const bf16x8*)&attn[(16*m + c) * XS_STRIDE + k0];
            oo[m] = __builtin_amdgcn_mfma_f32_16x16x32_bf16(a, bw, oo[m], 0, 0, 0);
        }
    }
    // transpose through LDS (f32) so the global scatter is row-contiguous
    float* outl = (float*)(smem + HEADS_BASE);    // [192][OUT_STRIDE], overlays dead head region
    const float ob = bout[colb + c];
    #pragma unroll
    for (int m = 0; m < 4; ++m)
        #pragma unroll
        for (int r = 0; r < 4; ++r)
            outl[(colb + c) * OUT_STRIDE + 16*m + 4*g + r] = oo[m][r] + ob;
    __syncthreads();

    for (int i = tid; i < 64 * C_; i += THREADS) {
        int ch = i >> 6, tok = i & 63;
        owin[(size_t)ch * (H_ * W_) + (tok >> 3) * W_ + (tok & 7)] = outl[ch * OUT_STRIDE + tok];
    }
}

extern "C" void kernel_launch(void* const* d_in, const int* in_sizes, int n_in,
                              void* d_out, int out_size, void* d_ws, size_t ws_size,
                              hipStream_t stream) {
    const float* x    = (const float*)d_in[0];
    const float* wqkv = (const float*)d_in[1];
    const float* bqkv = (const float*)d_in[2];
    const float* wout = (const float*)d_in[3];
    const float* bout = (const float*)d_in[4];
    float* out = (float*)d_out;

    hipFuncSetAttribute((const void*)block_attn,
                        hipFuncAttributeMaxDynamicSharedMemorySize, LDS_BYTES);
    block_attn<<<NWIN, THREADS, LDS_BYTES, stream>>>(x, wqkv, bqkv, wout, bout, out);
}

// Round 2
// 403.900 us; speedup vs baseline: 1.7341x; 1.7341x over previous
//
#include <hip/hip_runtime.h>
#include <hip/hip_bf16.h>

typedef __bf16 bf16;
typedef bf16  bf16x8 __attribute__((ext_vector_type(8)));
typedef float f32x4  __attribute__((ext_vector_type(4)));

#define DEVINL static __device__ __forceinline__

constexpr int C_ = 192, H_ = 256, W_ = 256;
constexpr int NH_ = 6;
constexpr int NWIN = 4096;          // 4 * 32 * 32 windows
constexpr int THREADS = 768;        // 12 waves: 2 per head
constexpr float QSCALE = 0.17677669529663687f;

// LDS layout (bf16 element strides; every ds_read_b128 16B-aligned)
constexpr int XS_STRIDE = 200;      // x window [64 tok][192 ch] + pad
constexpr int QK_STRIDE = 40;       // q/k [64 tok][32 hd] + pad
constexpr int VT_STRIDE = 72;       // vT [32 hd][64 tok] + pad
constexpr int P_STRIDE  = 72;       // p  [64 q ][64 key] + pad (overlays q+k)
constexpr int OUT_STRIDE = 67;      // out_lds f32 [192 ch][64 tok] + pad (overlays heads)

constexpr int XS_BYTES   = 64 * XS_STRIDE * 2;                                   // 25600
constexpr int HEAD_BYTES = (64*QK_STRIDE + 64*QK_STRIDE + 32*VT_STRIDE) * 2;     // 14848
constexpr int HEADS_BASE = XS_BYTES;
constexpr int LDS_BYTES  = HEADS_BASE + NH_ * HEAD_BYTES;                        // 114688

// workspace layout: bf16 wqkv (q-rows pre-scaled) | bf16 wout | f32 bqkv (q pre-scaled)
constexpr int WQKV_N = 576 * 192;
constexpr int WOUT_N = 192 * 192;
constexpr size_t WS_NEED = (size_t)(WQKV_N + WOUT_N) * 2 + 576 * 4;

DEVINL bf16x8 cvt8(const float* p) {
    float4 f0 = *(const float4*)p;
    float4 f1 = *(const float4*)(p + 4);
    bf16x8 r;
    r[0] = (bf16)f0.x; r[1] = (bf16)f0.y; r[2] = (bf16)f0.z; r[3] = (bf16)f0.w;
    r[4] = (bf16)f1.x; r[5] = (bf16)f1.y; r[6] = (bf16)f1.z; r[7] = (bf16)f1.w;
    return r;
}

__global__ void prep_weights(const float* __restrict__ wqkv, const float* __restrict__ bqkv,
                             const float* __restrict__ wout,
                             bf16* __restrict__ wq_b, bf16* __restrict__ wo_b,
                             float* __restrict__ bq_s) {
    int i = blockIdx.x * 256 + threadIdx.x;
    if (i < WQKV_N) {
        float v = wqkv[i];
        if (i < 192 * 192) v *= QSCALE;          // q rows pre-scaled
        wq_b[i] = (bf16)v;
    }
    int j = i - WQKV_N;
    if (j >= 0 && j < WOUT_N) wo_b[j] = (bf16)wout[j];
    int k2 = i - (WQKV_N + WOUT_N);
    if (k2 >= 0 && k2 < 576) bq_s[k2] = bqkv[k2] * (k2 < 192 ? QSCALE : 1.0f);
}

// One block per 8x8 window. 12 waves: wave = 2*head + half.
// MFMA 16x16x32 bf16 layouts (HW-verified per guide):
//   A[row=lane&15][k=(lane>>4)*8+j]  B[k=(lane>>4)*8+j][col=lane&15]
//   D[row=(lane>>4)*4+r][col=lane&15]
template<bool WB>
__global__ __launch_bounds__(THREADS, 1)
void block_attn(const float* __restrict__ x,
                const float* __restrict__ wqkv,   // [576][192] f32 (fallback)
                const float* __restrict__ bqkv,   // [576]      f32 (fallback)
                const float* __restrict__ wout,   // [192][192] f32 (fallback)
                const float* __restrict__ bout,   // [192]
                const bf16*  __restrict__ wq_b,   // [576][192] bf16, q pre-scaled
                const bf16*  __restrict__ wo_b,   // [192][192] bf16
                const float* __restrict__ bq_s,   // [576] f32, q pre-scaled
                float* __restrict__ out)
{
    extern __shared__ char smem[];
    bf16* xs = (bf16*)smem;                       // [64][XS_STRIDE]; later attn-out overlay

    const int tid  = threadIdx.x;
    const int lane = tid & 63;
    const int wv   = tid >> 6;       // 0..11
    const int h    = wv >> 1;        // head 0..5
    const int half = wv & 1;         // row-half of the window
    const int g    = lane >> 4;      // 0..3
    const int c    = lane & 15;

    // XCD-chunked swizzle: ww-adjacent windows land on the same XCD -> L2 line sharing
    const int win = (blockIdx.x & 7) * (NWIN / 8) + (blockIdx.x >> 3);
    const int b  = win >> 10;
    const int wh = (win >> 5) & 31;
    const int ww = win & 31;

    const size_t pixbase = ((size_t)b * C_) * (H_ * W_) + (size_t)(wh * 8) * W_ + ww * 8;
    const float* xwin = x   + pixbase;
    float*       owin = out + pixbase;

    // ---------------- phase 0: gather x window -> regs (all loads in flight) -> LDS bf16
    {
        float r[16];
        #pragma unroll
        for (int j = 0; j < 16; ++j) {
            const int ch = wv + 12 * j;
            r[j] = xwin[(size_t)ch * (H_ * W_) + (lane >> 3) * W_ + (lane & 7)];
        }
        #pragma unroll
        for (int j = 0; j < 16; ++j) {
            const int ch = wv + 12 * j;
            xs[lane * XS_STRIDE + ch] = (bf16)r[j];
        }
    }
    __syncthreads();

    bf16* qh  = (bf16*)(smem + HEADS_BASE + h * HEAD_BYTES);  // [64][QK_STRIDE]
    bf16* kh  = qh + 64 * QK_STRIDE;                          // [64][QK_STRIDE]
    bf16* vth = kh + 64 * QK_STRIDE;                          // [32][VT_STRIDE]
    bf16* ph  = qh;                                           // p overlays q+k (after barrier)

    const int colt[6] = {32*h, 32*h+16, 192+32*h, 192+32*h+16, 384+32*h, 384+32*h+16};
    const int m0 = 2 * half;  // this wave's row tiles: m0, m0+1

    // ---------------- phase 1: QKV projection for this head (96 cols), K=192
    f32x4 acc[2][6];
    #pragma unroll
    for (int i2 = 0; i2 < 2; ++i2)
        #pragma unroll
        for (int ct = 0; ct < 6; ++ct) acc[i2][ct] = (f32x4){0.f, 0.f, 0.f, 0.f};

    // preload all A fragments (12 x ds_read_b128)
    bf16x8 af0[6], af1[6];
    #pragma unroll
    for (int ks = 0; ks < 6; ++ks) {
        const int k0 = ks * 32 + g * 8;
        af0[ks] = *(const bf16x8*)&xs[(16*m0      + c) * XS_STRIDE + k0];
        af1[ks] = *(const bf16x8*)&xs[(16*m0 + 16 + c) * XS_STRIDE + k0];
    }
    // double-buffered weight fragments
    bf16x8 wcur[6], wnxt[6];
    #pragma unroll
    for (int ct = 0; ct < 6; ++ct) {
        if (WB) wcur[ct] = *(const bf16x8*)&wq_b[(size_t)(colt[ct] + c) * C_ + g * 8];
        else    wcur[ct] = cvt8(wqkv + (size_t)(colt[ct] + c) * C_ + g * 8);
    }
    #pragma unroll
    for (int ks = 0; ks < 6; ++ks) {
        if (ks < 5) {
            const int k1 = (ks + 1) * 32 + g * 8;
            #pragma unroll
            for (int ct = 0; ct < 6; ++ct) {
                if (WB) wnxt[ct] = *(const bf16x8*)&wq_b[(size_t)(colt[ct] + c) * C_ + k1];
                else    wnxt[ct] = cvt8(wqkv + (size_t)(colt[ct] + c) * C_ + k1);
            }
        }
        #pragma unroll
        for (int ct = 0; ct < 6; ++ct) {
            acc[0][ct] = __builtin_amdgcn_mfma_f32_16x16x32_bf16(af0[ks], wcur[ct], acc[0][ct], 0, 0, 0);
            acc[1][ct] = __builtin_amdgcn_mfma_f32_16x16x32_bf16(af1[ks], wcur[ct], acc[1][ct], 0, 0, 0);
        }
        #pragma unroll
        for (int ct = 0; ct < 6; ++ct) wcur[ct] = wnxt[ct];
    }

    // bias + store q (pre-scaled), k, vT to LDS
    #pragma unroll
    for (int i2 = 0; i2 < 2; ++i2) {
        const int trow = 16 * (m0 + i2) + 4 * g;
        #pragma unroll
        for (int ct = 0; ct < 6; ++ct) {
            const float bias = WB ? bq_s[colt[ct] + c] : bqkv[colt[ct] + c];
            #pragma unroll
            for (int r = 0; r < 4; ++r) {
                float v = acc[i2][ct][r] + bias;
                int tok = trow + r;
                if (ct < 2)       qh[tok * QK_STRIDE + 16*ct + c] = (bf16)(WB ? v : v * QSCALE);
                else if (ct < 4)  kh[tok * QK_STRIDE + 16*(ct-2) + c] = (bf16)v;
                else              vth[(16*(ct-4) + c) * VT_STRIDE + tok] = (bf16)v;  // transposed
            }
        }
    }
    __syncthreads();

    // ---------------- phase 2: scores = q @ k^T (K=32) + softmax
    f32x4 sc[2][4];
    {
        const f32x4 zf = (f32x4){0.f, 0.f, 0.f, 0.f};
        bf16x8 qa0 = *(const bf16x8*)&qh[(16*m0      + c) * QK_STRIDE + g * 8];
        bf16x8 qa1 = *(const bf16x8*)&qh[(16*m0 + 16 + c) * QK_STRIDE + g * 8];
        #pragma unroll
        for (int ct = 0; ct < 4; ++ct) {
            bf16x8 kb = *(const bf16x8*)&kh[(16*ct + c) * QK_STRIDE + g * 8];
            sc[0][ct] = __builtin_amdgcn_mfma_f32_16x16x32_bf16(qa0, kb, zf, 0, 0, 0);
            sc[1][ct] = __builtin_amdgcn_mfma_f32_16x16x32_bf16(qa1, kb, zf, 0, 0, 0);
        }
    }
    #pragma unroll
    for (int i2 = 0; i2 < 2; ++i2) {
        #pragma unroll
        for (int r = 0; r < 4; ++r) {
            float mx = fmaxf(fmaxf(sc[i2][0][r], sc[i2][1][r]), fmaxf(sc[i2][2][r], sc[i2][3][r]));
            mx = fmaxf(mx, __shfl_xor(mx, 1, 16));
            mx = fmaxf(mx, __shfl_xor(mx, 2, 16));
            mx = fmaxf(mx, __shfl_xor(mx, 4, 16));
            mx = fmaxf(mx, __shfl_xor(mx, 8, 16));
            float e0 = __expf(sc[i2][0][r] - mx);
            float e1 = __expf(sc[i2][1][r] - mx);
            float e2 = __expf(sc[i2][2][r] - mx);
            float e3 = __expf(sc[i2][3][r] - mx);
            float s = e0 + e1 + e2 + e3;
            s += __shfl_xor(s, 1, 16);
            s += __shfl_xor(s, 2, 16);
            s += __shfl_xor(s, 4, 16);
            s += __shfl_xor(s, 8, 16);
            float inv = 1.0f / s;
            sc[i2][0][r] = e0 * inv; sc[i2][1][r] = e1 * inv;
            sc[i2][2][r] = e2 * inv; sc[i2][3][r] = e3 * inv;
        }
    }
    __syncthreads();  // all waves done READING q/k before p overlays them

    #pragma unroll
    for (int i2 = 0; i2 < 2; ++i2)
        #pragma unroll
        for (int ct = 0; ct < 4; ++ct)
            #pragma unroll
            for (int r = 0; r < 4; ++r)
                ph[(16*(m0+i2) + 4*g + r) * P_STRIDE + 16*ct + c] = (bf16)sc[i2][ct][r];

    // ---------------- phase 3: out_h = p @ v  (reads only p rows this wave wrote)
    f32x4 oacc[2][2];
    #pragma unroll
    for (int i2 = 0; i2 < 2; ++i2)
        #pragma unroll
        for (int ct2 = 0; ct2 < 2; ++ct2) oacc[i2][ct2] = (f32x4){0.f, 0.f, 0.f, 0.f};

    #pragma unroll
    for (int ks2 = 0; ks2 < 2; ++ks2) {
        bf16x8 pa0 = *(const bf16x8*)&ph[(16*m0      + c) * P_STRIDE + ks2*32 + g*8];
        bf16x8 pa1 = *(const bf16x8*)&ph[(16*m0 + 16 + c) * P_STRIDE + ks2*32 + g*8];
        #pragma unroll
        for (int ct2 = 0; ct2 < 2; ++ct2) {
            bf16x8 vb = *(const bf16x8*)&vth[(16*ct2 + c) * VT_STRIDE + ks2*32 + g*8];
            oacc[0][ct2] = __builtin_amdgcn_mfma_f32_16x16x32_bf16(pa0, vb, oacc[0][ct2], 0, 0, 0);
            oacc[1][ct2] = __builtin_amdgcn_mfma_f32_16x16x32_bf16(pa1, vb, oacc[1][ct2], 0, 0, 0);
        }
    }
    bf16* attn = xs;  // attn-out [64 tok][192 ch] overlays xs (dead since phase 1)
    #pragma unroll
    for (int i2 = 0; i2 < 2; ++i2)
        #pragma unroll
        for (int ct2 = 0; ct2 < 2; ++ct2)
            #pragma unroll
            for (int r = 0; r < 4; ++r)
                attn[(16*(m0+i2) + 4*g + r) * XS_STRIDE + 32*h + 16*ct2 + c] = (bf16)oacc[i2][ct2][r];
    __syncthreads();

    // ---------------- phase 4: out-proj, wave wv owns cols [16*wv, 16*wv+16)
    const int colb = 16 * wv;
    bf16x8 wo[6];
    #pragma unroll
    for (int ks = 0; ks < 6; ++ks) {
        if (WB) wo[ks] = *(const bf16x8*)&wo_b[(size_t)(colb + c) * C_ + ks*32 + g*8];
        else    wo[ks] = cvt8(wout + (size_t)(colb + c) * C_ + ks*32 + g*8);
    }
    f32x4 oo[4];
    #pragma unroll
    for (int m = 0; m < 4; ++m) oo[m] = (f32x4){0.f, 0.f, 0.f, 0.f};
    #pragma unroll
    for (int ks = 0; ks < 6; ++ks) {
        const int k0 = ks * 32 + g * 8;
        #pragma unroll
        for (int m = 0; m < 4; ++m) {
            bf16x8 a = *(const bf16x8*)&attn[(16*m + c) * XS_STRIDE + k0];
            oo[m] = __builtin_amdgcn_mfma_f32_16x16x32_bf16(a, wo[ks], oo[m], 0, 0, 0);
        }
    }
    // transpose through LDS (f32) so the global scatter is row-contiguous
    float* outl = (float*)(smem + HEADS_BASE);    // [192][OUT_STRIDE], overlays dead head region
    const float ob = bout[colb + c];
    #pragma unroll
    for (int m = 0; m < 4; ++m)
        #pragma unroll
        for (int r = 0; r < 4; ++r)
            outl[(colb + c) * OUT_STRIDE + 16*m + 4*g + r] = oo[m][r] + ob;
    __syncthreads();

    // ---------------- phase 5: scatter to [B,C,H,W]
    #pragma unroll
    for (int j = 0; j < 16; ++j) {
        const int ch = wv + 12 * j;
        owin[(size_t)ch * (H_ * W_) + (lane >> 3) * W_ + (lane & 7)] = outl[ch * OUT_STRIDE + lane];
    }
}

extern "C" void kernel_launch(void* const* d_in, const int* in_sizes, int n_in,
                              void* d_out, int out_size, void* d_ws, size_t ws_size,
                              hipStream_t stream) {
    const float* x    = (const float*)d_in[0];
    const float* wqkv = (const float*)d_in[1];
    const float* bqkv = (const float*)d_in[2];
    const float* wout = (const float*)d_in[3];
    const float* bout = (const float*)d_in[4];
    float* out = (float*)d_out;

    bf16*  wq_b = (bf16*)d_ws;
    bf16*  wo_b = wq_b + WQKV_N;
    float* bq_s = (float*)(wo_b + WOUT_N);

    const bool wb = (ws_size >= WS_NEED) && (d_ws != nullptr);

    if (wb) {
        hipFuncSetAttribute((const void*)block_attn<true>,
                            hipFuncAttributeMaxDynamicSharedMemorySize, LDS_BYTES);
        prep_weights<<<(WQKV_N + WOUT_N + 576 + 255) / 256, 256, 0, stream>>>(
            wqkv, bqkv, wout, wq_b, wo_b, bq_s);
        block_attn<true><<<NWIN, THREADS, LDS_BYTES, stream>>>(
            x, wqkv, bqkv, wout, bout, wq_b, wo_b, bq_s, out);
    } else {
        hipFuncSetAttribute((const void*)block_attn<false>,
                            hipFuncAttributeMaxDynamicSharedMemorySize, LDS_BYTES);
        block_attn<false><<<NWIN, THREADS, LDS_BYTES, stream>>>(
            x, wqkv, bqkv, wout, bout, wq_b, wo_b, bq_s, out);
    }
}